// Round 1
// baseline (383.977 us; speedup 1.0000x reference)
//
#include <hip/hip_runtime.h>
#include <hip/hip_bf16.h>

// Problem constants (from reference)
#define NN 100000
#define KK 32
#define DD 128   // D_IN == D_OUT == 128
// remove = floor(32*0.45) = 14 -> keep sorted ranks [14,18), mean of 4

// ---------------------------------------------------------------------------
// Kernel 1: h = x @ W^T   (h[n][o] = sum_d x[n][d] * W[o][d]), fp32.
// Block = 256 threads, tile = 32 rows x 128 cols.
// x tile staged in LDS (16 KB); W read from global (64 KB total, L2-resident).
// Thread (o = tid&127, half = tid>>7) computes 16 rows for its column o.
// ---------------------------------------------------------------------------
__global__ __launch_bounds__(256)
void gemm_xwT_kernel(const float* __restrict__ x, const float* __restrict__ W,
                     float* __restrict__ h) {
    __shared__ float xs[32][DD];

    const int tid = threadIdx.x;
    const int block_row = blockIdx.x * 32;

    // cooperative load of 32x128 x-tile as float4: 1024 float4 / 256 threads
    {
        const float4* xsrc = (const float4*)(x + (size_t)block_row * DD);
        float4* xdst = (float4*)&xs[0][0];
        #pragma unroll
        for (int t = 0; t < 4; ++t)
            xdst[tid + 256 * t] = xsrc[tid + 256 * t];
    }
    __syncthreads();

    const int o  = tid & 127;
    const int r0 = (tid >> 7) * 16;

    float acc[16];
    #pragma unroll
    for (int r = 0; r < 16; ++r) acc[r] = 0.0f;

    const float4* wrow = (const float4*)(W + (size_t)o * DD);
    #pragma unroll 4
    for (int d4 = 0; d4 < DD / 4; ++d4) {
        float4 w4 = wrow[d4];
        #pragma unroll
        for (int r = 0; r < 16; ++r) {
            float4 x4 = *(const float4*)(&xs[r0 + r][d4 * 4]);
            acc[r] += x4.x * w4.x + x4.y * w4.y + x4.z * w4.z + x4.w * w4.w;
        }
    }

    #pragma unroll
    for (int r = 0; r < 16; ++r) {
        h[(size_t)(block_row + r0 + r) * DD + o] = acc[r];
    }
}

// ---------------------------------------------------------------------------
// Kernel 2: per (n, o): gather 32 values h[nbrs[n][k]][o], bitonic-sort in
// registers, output mean of sorted ranks 14..17.
// Block = 256 threads = 2 rows x 128 channels. Waves are row-uniform
// (lanes 0..127 -> row 0), so the LDS index reads are wave-broadcast.
// ---------------------------------------------------------------------------
__global__ __launch_bounds__(256)
void trimmed_mean_kernel(const float* __restrict__ h, const int* __restrict__ nbrs,
                         float* __restrict__ out) {
    __shared__ int s_nbr[2][KK];

    const int tid = threadIdx.x;
    const int row_base = blockIdx.x * 2;

    if (tid < 64) {
        const int r = tid >> 5;       // 0..1
        const int k = tid & 31;       // 0..31
        s_nbr[r][k] = nbrs[(size_t)(row_base + r) * KK + k];
    }
    __syncthreads();

    const int o   = tid & 127;
    const int sub = tid >> 7;         // 0..1
    const int row = row_base + sub;

    float v[KK];
    #pragma unroll
    for (int k = 0; k < KK; ++k) {
        const int idx = s_nbr[sub][k];
        v[k] = h[(size_t)idx * DD + o];
    }

    // Branchless bitonic sort, ascending. Fully unrolled -> registers only.
    #pragma unroll
    for (int k = 2; k <= KK; k <<= 1) {
        #pragma unroll
        for (int j = k >> 1; j > 0; j >>= 1) {
            #pragma unroll
            for (int i = 0; i < KK; ++i) {
                const int l = i ^ j;
                if (l > i) {
                    const bool up = ((i & k) == 0);
                    const float a = v[i], b = v[l];
                    const float lo = fminf(a, b), hi = fmaxf(a, b);
                    v[i] = up ? lo : hi;
                    v[l] = up ? hi : lo;
                }
            }
        }
    }

    out[(size_t)row * DD + o] = (v[14] + v[15] + v[16] + v[17]) * 0.25f;
}

extern "C" void kernel_launch(void* const* d_in, const int* in_sizes, int n_in,
                              void* d_out, int out_size, void* d_ws, size_t ws_size,
                              hipStream_t stream) {
    const float* x    = (const float*)d_in[0];   // (N, 128) fp32
    const float* W    = (const float*)d_in[1];   // (128, 128) fp32
    const int*   nbrs = (const int*)d_in[2];     // (N, 32) int32
    float*       out  = (float*)d_out;           // (N, 128) fp32
    float*       h    = (float*)d_ws;            // scratch: N*128 fp32 = 51.2 MB

    (void)in_sizes; (void)n_in; (void)out_size; (void)ws_size;

    // h = x @ W^T : 100000/32 = 3125 blocks exactly
    gemm_xwT_kernel<<<NN / 32, 256, 0, stream>>>(x, W, h);

    // trimmed mean: 100000/2 = 50000 blocks exactly
    trimmed_mean_kernel<<<NN / 2, 256, 0, stream>>>(h, nbrs, out);
}

// Round 3
// 230.328 us; speedup vs baseline: 1.6671x; 1.6671x over previous
//
#include <hip/hip_runtime.h>
#include <hip/hip_fp16.h>

// Problem constants (from reference)
#define NN 100000
#define KK 32
#define DD 128
// remove = floor(32*0.45) = 14 -> keep sorted ranks [14,18), mean of 4

typedef _Float16 v8h __attribute__((ext_vector_type(8)));
typedef _Float16 v4h __attribute__((ext_vector_type(4)));
typedef _Float16 v2h __attribute__((ext_vector_type(2)));
typedef float    v4f __attribute__((ext_vector_type(4)));

#define LDH 136   // padded LDS row stride in f16 (128 + 8): 272 B = 17*16 B

// ---------------------------------------------------------------------------
// Kernel 1: h = x @ W^T in f16 via MFMA 16x16x32.
// Block = 256 threads (4 waves), tile = 128 x-rows. W (128x128) and x-tile
// staged in LDS as f16 (+8 pad -> only 2-way bank aliasing, free).
// Operand mapping: A = W rows (D-rows = o), B = x rows (D-cols = n), so each
// lane's 4 acc elements are 4 consecutive o -> one 8B f16 store per tile.
// ---------------------------------------------------------------------------
__global__ __launch_bounds__(256)
void gemm_mfma_kernel(const float* __restrict__ x, const float* __restrict__ W,
                      _Float16* __restrict__ h) {
    __shared__ _Float16 w_lds[DD * LDH];    // 34816 B
    __shared__ _Float16 x_lds[128 * LDH];   // 34816 B

    const int tid = threadIdx.x;
    const int block_row = blockIdx.x * 128;

    // stage W: 4096 float4 / 256 threads = 16 each
    {
        const float4* ws = (const float4*)W;
        #pragma unroll
        for (int t = 0; t < 16; ++t) {
            const int fi = tid + 256 * t;
            const int r = fi >> 5, c4 = fi & 31;
            const float4 f = ws[fi];
            v4h p = { (_Float16)f.x, (_Float16)f.y, (_Float16)f.z, (_Float16)f.w };
            *(v4h*)&w_lds[r * LDH + c4 * 4] = p;
        }
    }
    // stage x tile (guard tail rows)
    {
        const float4* xs = (const float4*)x;
        #pragma unroll
        for (int t = 0; t < 16; ++t) {
            const int fi = tid + 256 * t;
            const int r = fi >> 5, c4 = fi & 31;
            const int gr = block_row + r;
            float4 f = make_float4(0.f, 0.f, 0.f, 0.f);
            if (gr < NN) f = xs[(size_t)gr * 32 + c4];
            v4h p = { (_Float16)f.x, (_Float16)f.y, (_Float16)f.z, (_Float16)f.w };
            *(v4h*)&x_lds[r * LDH + c4 * 4] = p;
        }
    }
    __syncthreads();

    const int wv   = tid >> 6;    // wave 0..3: x-rows [wv*32, wv*32+32)
    const int lane = tid & 63;
    const int m    = lane & 15;
    const int quad = lane >> 4;

    const v4f zero = {0.f, 0.f, 0.f, 0.f};
    v4f acc[2][8];
    #pragma unroll
    for (int nt = 0; nt < 2; ++nt)
        #pragma unroll
        for (int ot = 0; ot < 8; ++ot) acc[nt][ot] = zero;

    #pragma unroll
    for (int ks = 0; ks < 4; ++ks) {
        const int kb = ks * 32 + quad * 8;
        const v8h xf0 = *(const v8h*)&x_lds[(wv * 32 + m) * LDH + kb];
        const v8h xf1 = *(const v8h*)&x_lds[(wv * 32 + 16 + m) * LDH + kb];
        #pragma unroll
        for (int ot = 0; ot < 8; ++ot) {
            const v8h wf = *(const v8h*)&w_lds[(ot * 16 + m) * LDH + kb];
            acc[0][ot] = __builtin_amdgcn_mfma_f32_16x16x32_f16(wf, xf0, acc[0][ot], 0, 0, 0);
            acc[1][ot] = __builtin_amdgcn_mfma_f32_16x16x32_f16(wf, xf1, acc[1][ot], 0, 0, 0);
        }
    }

    // store: D[row=o=quad*4+reg][col=n=m]; lane's 4 regs = 4 consecutive o
    #pragma unroll
    for (int nt = 0; nt < 2; ++nt) {
        const int xr = block_row + wv * 32 + nt * 16 + m;
        if (xr < NN) {
            #pragma unroll
            for (int ot = 0; ot < 8; ++ot) {
                const v4f a = acc[nt][ot];
                v4h p = { (_Float16)a.x, (_Float16)a.y, (_Float16)a.z, (_Float16)a.w };
                *(v4h*)&h[(size_t)xr * DD + ot * 16 + quad * 4] = p;
            }
        }
    }
}

// ---------------------------------------------------------------------------
// Kernel 2: per (n, channel-pair): gather 32 packed-f16 values, sort both
// f16 lanes simultaneously with v_pk_min/max_f16 (__builtin_elementwise_*),
// output mean of sorted ranks 14..17. Final bitonic merge pruned to outputs
// {14..17}: 206 CEs instead of 240.
// Block = 256 threads = 4 rows x 64 channel-pairs; each wave is row-uniform.
// ---------------------------------------------------------------------------
#define CEA(i, l) do { const v2h lo_ = __builtin_elementwise_min(v[i], v[l]); \
                       const v2h hi_ = __builtin_elementwise_max(v[i], v[l]); \
                       v[i] = lo_; v[l] = hi_; } while (0)
#define CED(i, l) do { const v2h lo_ = __builtin_elementwise_min(v[i], v[l]); \
                       const v2h hi_ = __builtin_elementwise_max(v[i], v[l]); \
                       v[i] = hi_; v[l] = lo_; } while (0)

__global__ __launch_bounds__(256)
void trimmed_mean_kernel(const _Float16* __restrict__ h, const int* __restrict__ nbrs,
                         float* __restrict__ out) {
    __shared__ int s_nbr[4][KK];

    const int tid = threadIdx.x;
    const int row_base = blockIdx.x * 4;

    if (tid < 128)
        s_nbr[tid >> 5][tid & 31] = nbrs[(size_t)row_base * KK + tid];
    __syncthreads();

    const int c   = tid & 63;     // channel pair: channels (2c, 2c+1)
    const int sub = tid >> 6;     // row within block (wave-uniform)
    const int row = row_base + sub;

    const v2h* hb = (const v2h*)h;   // row stride = 64 v2h

    v2h v[KK];
    #pragma unroll
    for (int k = 0; k < KK; ++k) {
        const int idx = s_nbr[sub][k];
        v[k] = hb[(size_t)idx * 64 + c];
    }

    // Stages k=2..16: produce bitonic sequence (0..15 asc, 16..31 desc).
    #pragma unroll
    for (int k = 2; k <= 16; k <<= 1) {
        #pragma unroll
        for (int j = k >> 1; j > 0; j >>= 1) {
            #pragma unroll
            for (int i = 0; i < KK; ++i) {
                const int l = i ^ j;
                if (l > i) {
                    if ((i & k) == 0) CEA(i, l);
                    else              CED(i, l);
                }
            }
        }
    }
    // Final ascending merge (k=32), pruned to outputs {14,15,16,17}.
    #pragma unroll
    for (int i = 0; i < 16; ++i) CEA(i, i + 16);                        // j=16
    #pragma unroll
    for (int i = 0; i < 8; ++i) { CEA(i, i + 8); CEA(i + 16, i + 24); } // j=8
    CEA(8, 12); CEA(9, 13); CEA(10, 14); CEA(11, 15);                   // j=4
    CEA(16, 20); CEA(17, 21); CEA(18, 22); CEA(19, 23);
    CEA(12, 14); CEA(13, 15); CEA(16, 18); CEA(17, 19);                 // j=2
    CEA(14, 15); CEA(16, 17);                                           // j=1

    float2 o2;
    o2.x = ((float)v[14].x + (float)v[15].x + (float)v[16].x + (float)v[17].x) * 0.25f;
    o2.y = ((float)v[14].y + (float)v[15].y + (float)v[16].y + (float)v[17].y) * 0.25f;
    ((float2*)(out + (size_t)row * DD))[c] = o2;
}

extern "C" void kernel_launch(void* const* d_in, const int* in_sizes, int n_in,
                              void* d_out, int out_size, void* d_ws, size_t ws_size,
                              hipStream_t stream) {
    const float* x    = (const float*)d_in[0];   // (N, 128) fp32
    const float* W    = (const float*)d_in[1];   // (128, 128) fp32
    const int*   nbrs = (const int*)d_in[2];     // (N, 32) int32
    float*       out  = (float*)d_out;           // (N, 128) fp32
    _Float16*    h    = (_Float16*)d_ws;         // scratch: N*128 f16 = 25.6 MB

    (void)in_sizes; (void)n_in; (void)out_size; (void)ws_size;

    gemm_mfma_kernel<<<(NN + 127) / 128, 256, 0, stream>>>(x, W, h);   // 782 blocks
    trimmed_mean_kernel<<<NN / 4, 256, 0, stream>>>(h, nbrs, out);     // 25000 blocks
}

// Round 4
// 227.623 us; speedup vs baseline: 1.6869x; 1.0119x over previous
//
#include <hip/hip_runtime.h>
#include <hip/hip_fp16.h>

// Problem constants (from reference)
#define NN 100000
#define KK 32
#define DD 128
// remove = floor(32*0.45) = 14 -> keep sorted ranks [14,18), mean of 4

typedef _Float16 v8h __attribute__((ext_vector_type(8)));
typedef _Float16 v4h __attribute__((ext_vector_type(4)));
typedef _Float16 v2h __attribute__((ext_vector_type(2)));
typedef float    v4f __attribute__((ext_vector_type(4)));

#define LDH 136   // padded LDS row stride in f16 (128 + 8): 272 B = 17*16 B

// ---------------------------------------------------------------------------
// Kernel 1 (unchanged from round 3, ~15 us, near memory floor):
// h = x @ W^T in f16 via MFMA 16x16x32.
// ---------------------------------------------------------------------------
__global__ __launch_bounds__(256)
void gemm_mfma_kernel(const float* __restrict__ x, const float* __restrict__ W,
                      _Float16* __restrict__ h) {
    __shared__ _Float16 w_lds[DD * LDH];
    __shared__ _Float16 x_lds[128 * LDH];

    const int tid = threadIdx.x;
    const int block_row = blockIdx.x * 128;

    {
        const float4* ws = (const float4*)W;
        #pragma unroll
        for (int t = 0; t < 16; ++t) {
            const int fi = tid + 256 * t;
            const int r = fi >> 5, c4 = fi & 31;
            const float4 f = ws[fi];
            v4h p = { (_Float16)f.x, (_Float16)f.y, (_Float16)f.z, (_Float16)f.w };
            *(v4h*)&w_lds[r * LDH + c4 * 4] = p;
        }
    }
    {
        const float4* xs = (const float4*)x;
        #pragma unroll
        for (int t = 0; t < 16; ++t) {
            const int fi = tid + 256 * t;
            const int r = fi >> 5, c4 = fi & 31;
            const int gr = block_row + r;
            float4 f = make_float4(0.f, 0.f, 0.f, 0.f);
            if (gr < NN) f = xs[(size_t)gr * 32 + c4];
            v4h p = { (_Float16)f.x, (_Float16)f.y, (_Float16)f.z, (_Float16)f.w };
            *(v4h*)&x_lds[r * LDH + c4 * 4] = p;
        }
    }
    __syncthreads();

    const int wv   = tid >> 6;
    const int lane = tid & 63;
    const int m    = lane & 15;
    const int quad = lane >> 4;

    const v4f zero = {0.f, 0.f, 0.f, 0.f};
    v4f acc[2][8];
    #pragma unroll
    for (int nt = 0; nt < 2; ++nt)
        #pragma unroll
        for (int ot = 0; ot < 8; ++ot) acc[nt][ot] = zero;

    #pragma unroll
    for (int ks = 0; ks < 4; ++ks) {
        const int kb = ks * 32 + quad * 8;
        const v8h xf0 = *(const v8h*)&x_lds[(wv * 32 + m) * LDH + kb];
        const v8h xf1 = *(const v8h*)&x_lds[(wv * 32 + 16 + m) * LDH + kb];
        #pragma unroll
        for (int ot = 0; ot < 8; ++ot) {
            const v8h wf = *(const v8h*)&w_lds[(ot * 16 + m) * LDH + kb];
            acc[0][ot] = __builtin_amdgcn_mfma_f32_16x16x32_f16(wf, xf0, acc[0][ot], 0, 0, 0);
            acc[1][ot] = __builtin_amdgcn_mfma_f32_16x16x32_f16(wf, xf1, acc[1][ot], 0, 0, 0);
        }
    }

    #pragma unroll
    for (int nt = 0; nt < 2; ++nt) {
        const int xr = block_row + wv * 32 + nt * 16 + m;
        if (xr < NN) {
            #pragma unroll
            for (int ot = 0; ot < 8; ++ot) {
                const v4f a = acc[nt][ot];
                v4h p = { (_Float16)a.x, (_Float16)a.y, (_Float16)a.z, (_Float16)a.w };
                *(v4h*)&h[(size_t)xr * DD + ot * 16 + quad * 4] = p;
            }
        }
    }
}

// ---------------------------------------------------------------------------
// Compile-time Batcher odd-even mergesort network for 16 elements (63 CEs).
// Correct by construction (classic recursion).
// ---------------------------------------------------------------------------
struct CEp { signed char a, b; };
struct Net16 { CEp ce[63]; };

constexpr int oem_merge(CEp* out, int c, int lo, int n, int r) {
    const int m = r * 2;
    if (m < n) {
        c = oem_merge(out, c, lo, n, m);
        c = oem_merge(out, c, lo + r, n, m);
        for (int i = lo + r; i + r < lo + n; i += m) {
            out[c].a = (signed char)i; out[c].b = (signed char)(i + r); ++c;
        }
    } else {
        out[c].a = (signed char)lo; out[c].b = (signed char)(lo + r); ++c;
    }
    return c;
}
constexpr int oem_sort(CEp* out, int c, int lo, int n) {
    if (n > 1) {
        const int m = n / 2;
        c = oem_sort(out, c, lo, m);
        c = oem_sort(out, c, lo + m, m);
        c = oem_merge(out, c, lo, n, 1);
    }
    return c;
}
constexpr Net16 make_net16() {
    Net16 net{};
    (void)oem_sort(net.ce, 0, 0, 16);   // fills exactly 63 CEs
    return net;
}
constexpr Net16 NET16 = make_net16();

// w-index -> v-index map for the final bitonic merge: w = [v0..v15 asc,
// v31..v16 (i.e. second half reversed -> descending)] is bitonic.
constexpr int WMAP(int i) { return i < 16 ? i : 47 - i; }

// ---------------------------------------------------------------------------
// Kernel 2: per (n, 4-channel group): gather 32 x 8B (4 f16 channels), sort
// all 4 channels simultaneously with forced v_pk_min/max_f16 (2 ch per op,
// two v2h register arrays), trimmed mean of ranks 14..17.
// Network: 2 x Batcher-16 (63 CE each) + pruned bitonic merge (44 CE) = 170.
// Block = 256 threads = 8 rows x 32 channel-quads.
// ---------------------------------------------------------------------------
#define PKMIN(d, s0, s1) asm("v_pk_min_f16 %0, %1, %2" : "=v"(d) : "v"(s0), "v"(s1))
#define PKMAX(d, s0, s1) asm("v_pk_max_f16 %0, %1, %2" : "=v"(d) : "v"(s0), "v"(s1))

// ascending compare-exchange on v-indices (p gets min, q gets max)
#define CEW(p, q) do {                                                  \
    v2h na_, xa_, nb_, xb_;                                             \
    PKMIN(na_, va[p], va[q]); PKMAX(xa_, va[p], va[q]);                 \
    PKMIN(nb_, vb[p], vb[q]); PKMAX(xb_, vb[p], vb[q]);                 \
    va[p] = na_; va[q] = xa_; vb[p] = nb_; vb[q] = xb_; } while (0)

__global__ __launch_bounds__(256)
void trimmed_mean_kernel(const _Float16* __restrict__ h, const int* __restrict__ nbrs,
                         float* __restrict__ out) {
    __shared__ int s_nbr[8][KK];

    const int tid = threadIdx.x;
    const int row_base = blockIdx.x * 8;

    s_nbr[tid >> 5][tid & 31] = nbrs[(size_t)row_base * KK + tid];
    __syncthreads();

    const int brow = tid >> 5;        // row within block, 0..7
    const int cq   = tid & 31;        // channel quad: channels [4cq, 4cq+4)
    const int row  = row_base + brow;

    const uint2* hq = (const uint2*)h;   // 8B units; row stride = 32

    v2h va[KK];   // channels 4cq, 4cq+1
    v2h vb[KK];   // channels 4cq+2, 4cq+3
    #pragma unroll
    for (int k = 0; k < KK; ++k) {
        const int idx = s_nbr[brow][k];
        const uint2 u = hq[idx * 32 + cq];
        va[k] = __builtin_bit_cast(v2h, u.x);
        vb[k] = __builtin_bit_cast(v2h, u.y);
    }

    // Sort both 16-halves ascending (Batcher odd-even mergesort, 63 CE each).
    #pragma unroll
    for (int t = 0; t < 63; ++t) CEW(NET16.ce[t].a, NET16.ce[t].b);
    #pragma unroll
    for (int t = 0; t < 63; ++t) CEW(NET16.ce[t].a + 16, NET16.ce[t].b + 16);

    // Bitonic merge on w = [asc half A, reversed half B], pruned to the
    // middle-4 SET (ranks 14..17 land at w14,w15,w16,w17; internal order
    // irrelevant for the mean, so the j=1 stage is dropped).
    #pragma unroll
    for (int i = 0; i < 16; ++i) CEW(WMAP(i), WMAP(i + 16));               // j=16
    #pragma unroll
    for (int i = 0; i < 8; ++i) { CEW(WMAP(i), WMAP(i + 8));               // j=8
                                  CEW(WMAP(i + 16), WMAP(i + 24)); }
    #pragma unroll
    for (int i = 8; i < 12; ++i) { CEW(WMAP(i), WMAP(i + 4));              // j=4
                                   CEW(WMAP(i + 8), WMAP(i + 12)); }
    CEW(WMAP(12), WMAP(14)); CEW(WMAP(13), WMAP(15));                      // j=2
    CEW(WMAP(16), WMAP(18)); CEW(WMAP(17), WMAP(19));

    // w14=v[14], w15=v[15], w16=v[31], w17=v[30]
    float4 o;
    o.x = ((float)va[14].x + (float)va[15].x + (float)va[31].x + (float)va[30].x) * 0.25f;
    o.y = ((float)va[14].y + (float)va[15].y + (float)va[31].y + (float)va[30].y) * 0.25f;
    o.z = ((float)vb[14].x + (float)vb[15].x + (float)vb[31].x + (float)vb[30].x) * 0.25f;
    o.w = ((float)vb[14].y + (float)vb[15].y + (float)vb[31].y + (float)vb[30].y) * 0.25f;
    ((float4*)(out + (size_t)row * DD))[cq] = o;
}

extern "C" void kernel_launch(void* const* d_in, const int* in_sizes, int n_in,
                              void* d_out, int out_size, void* d_ws, size_t ws_size,
                              hipStream_t stream) {
    const float* x    = (const float*)d_in[0];   // (N, 128) fp32
    const float* W    = (const float*)d_in[1];   // (128, 128) fp32
    const int*   nbrs = (const int*)d_in[2];     // (N, 32) int32
    float*       out  = (float*)d_out;           // (N, 128) fp32
    _Float16*    h    = (_Float16*)d_ws;         // scratch: N*128 f16 = 25.6 MB

    (void)in_sizes; (void)n_in; (void)out_size; (void)ws_size;

    gemm_mfma_kernel<<<(NN + 127) / 128, 256, 0, stream>>>(x, W, h);   // 782 blocks
    trimmed_mean_kernel<<<NN / 8, 256, 0, stream>>>(h, nbrs, out);     // 12500 blocks
}